// Round 1
// baseline (1279.794 us; speedup 1.0000x reference)
//
#include <hip/hip_runtime.h>
#include <stdint.h>

// LSTM: B=2048, T=512, F=32, H=128, G=4H=512. 2 layers + FC(128->1).
// One WG (512 thr, 8 waves) per 8 batch rows; 256 WGs = 1/CU.
// All matmuls: mfma_f32_16x16x32_f16, weights held in VGPRs as B-fragments.
// Wave w owns gate tiles {w, 8+w, 16+w, 24+w} == i,f,g,o for h-cols [16w,16w+16).
// M-tile = 16 rows: 8 real rows duplicated (A-frag row = lane&7); q-groups 2,3
// process the duplicate copies' upper acc regs so gate VALU covers 2 rows/lane.
// Layer-0 h sequence staged in d_ws as fp16 (needs 2048*512*128*2 = 256 MiB).

#define B_ 2048
#define T_ 512
#define F_ 32
#define H_ 128

typedef _Float16 half8 __attribute__((ext_vector_type(8)));
typedef float float4_t __attribute__((ext_vector_type(4)));

__device__ __forceinline__ float fsig(float xv) {
  return __builtin_amdgcn_rcpf(1.0f + __expf(-xv));
}
// overflow-safe tanh: e=inf -> 1, e=0 -> -1 (no NaN)
__device__ __forceinline__ float ftanh_(float xv) {
  float e = __expf(2.0f * xv);
  return 1.0f - 2.0f * __builtin_amdgcn_rcpf(1.0f + e);
}
__device__ __forceinline__ half8 cvt2f4(float4_t a, float4_t b) {
  half8 r;
  r[0] = (_Float16)a[0]; r[1] = (_Float16)a[1]; r[2] = (_Float16)a[2]; r[3] = (_Float16)a[3];
  r[4] = (_Float16)b[0]; r[5] = (_Float16)b[1]; r[6] = (_Float16)b[2]; r[7] = (_Float16)b[3];
  return r;
}
__device__ __forceinline__ half8 load8cvt(const float* p) {
  return cvt2f4(*(const float4_t*)p, *(const float4_t*)(p + 4));
}

__global__ __launch_bounds__(512, 2) void lstm_fused(
    const float* __restrict__ x, const float* __restrict__ Wih0,
    const float* __restrict__ Whh0, const float* __restrict__ b0,
    const float* __restrict__ Wih1, const float* __restrict__ Whh1,
    const float* __restrict__ b1, const float* __restrict__ Wfc,
    const float* __restrict__ bfc, float* __restrict__ out,
    _Float16* __restrict__ h0ws)
{
  // 136-half row stride (272 B = 17*16 B): b128 A-frag reads land 8 lanes per
  // 16B bank-group -> conflict-free. Double-buffered: 1 barrier per step.
  __shared__ __attribute__((aligned(16))) _Float16 lds_h[2][8 * 136];
  __shared__ float lds_fc[8][8];

  const int tid  = threadIdx.x;
  const int w    = tid >> 6;        // wave 0..7
  const int lane = tid & 63;
  const int n    = lane & 15;       // D col within tile / A-frag row
  const int q    = lane >> 4;       // quad
  const int rbase = (int)blockIdx.x * 8;
  const int rload = rbase + (n & 7);        // global row for A-frag loads
  const int rsh  = (q >> 1) * 2;            // which acc regs this lane finalizes
  const int rowq = (q & 1) * 4;             // base output row

  // ---------------- Phase 1 : layer 0 (x -> h0 sequence in ws) ----------------
  {
    half8 bwih[4];        // Wih0 B-frags (K=32, one chunk)
    half8 bwhh[4][4];     // Whh0 B-frags [tile][kc]
    float bias[4];
#pragma unroll
    for (int j = 0; j < 4; ++j) {
      const int g = (j * 8 + w) * 16 + n;   // global gate row
      bwih[j] = load8cvt(Wih0 + g * F_ + q * 8);
      bias[j] = b0[g];
#pragma unroll
      for (int kc = 0; kc < 4; ++kc)
        bwhh[j][kc] = load8cvt(Whh0 + g * H_ + kc * 32 + q * 8);
    }
    half8 ah[4];
#pragma unroll
    for (int kc = 0; kc < 4; ++kc)
#pragma unroll
      for (int e = 0; e < 8; ++e) ah[kc][e] = (_Float16)0.0f;
    float c0v = 0.f, c1v = 0.f;
    half8 ax = load8cvt(x + rload * (T_ * F_) + q * 8);   // t=0

#pragma unroll 1
    for (int t = 0; t < T_; ++t) {
      // prefetch next step's x
      const int tn = (t + 1 < T_) ? (t + 1) : t;
      const float* xp = x + rload * (T_ * F_) + tn * F_ + q * 8;
      const float4_t xa = *(const float4_t*)xp;
      const float4_t xb = *(const float4_t*)(xp + 4);

      float4_t acc[4];
#pragma unroll
      for (int j = 0; j < 4; ++j)
        acc[j] = (float4_t){bias[j], bias[j], bias[j], bias[j]};
#pragma unroll
      for (int j = 0; j < 4; ++j)
        acc[j] = __builtin_amdgcn_mfma_f32_16x16x32_f16(ax, bwih[j], acc[j], 0, 0, 0);
#pragma unroll
      for (int kc = 0; kc < 4; ++kc)
#pragma unroll
        for (int j = 0; j < 4; ++j)
          acc[j] = __builtin_amdgcn_mfma_f32_16x16x32_f16(ah[kc], bwhh[j][kc], acc[j], 0, 0, 0);

      _Float16* hb = lds_h[t & 1];
#pragma unroll
      for (int rr = 0; rr < 2; ++rr) {
        const int ri = rsh + rr;
        const float gi = fsig(acc[0][ri]);
        const float gf = fsig(acc[1][ri]);
        const float gg = ftanh_(acc[2][ri]);
        const float go = fsig(acc[3][ri]);
        float& cc = rr ? c1v : c0v;
        cc = gf * cc + gi * gg;
        const float hv = go * ftanh_(cc);
        const int row = rowq + ri;              // 0..7, each exactly once
        const _Float16 h16 = (_Float16)hv;
        hb[row * 136 + w * 16 + n] = h16;
        h0ws[((rbase + row) * T_ + t) * H_ + w * 16 + n] = h16;
      }
      __syncthreads();
#pragma unroll
      for (int kc = 0; kc < 4; ++kc)
        ah[kc] = *(const half8*)(hb + (n & 7) * 136 + kc * 32 + q * 8);
      ax = cvt2f4(xa, xb);
    }
  }

  __syncthreads();

  // ---------------- Phase 2 : layer 1 + FC ----------------
  {
    half8 bwih[4][4];
    half8 bwhh[4][4];
    float bias[4];
#pragma unroll
    for (int j = 0; j < 4; ++j) {
      const int g = (j * 8 + w) * 16 + n;
      bias[j] = b1[g];
#pragma unroll
      for (int kc = 0; kc < 4; ++kc) {
        bwih[j][kc] = load8cvt(Wih1 + g * H_ + kc * 32 + q * 8);
        bwhh[j][kc] = load8cvt(Whh1 + g * H_ + kc * 32 + q * 8);
      }
    }
    const float wfc = Wfc[w * 16 + n];
    half8 ah[4];
#pragma unroll
    for (int kc = 0; kc < 4; ++kc)
#pragma unroll
      for (int e = 0; e < 8; ++e) ah[kc][e] = (_Float16)0.0f;
    float c0v = 0.f, c1v = 0.f, hl0 = 0.f, hl1 = 0.f;

    const _Float16* h0p = h0ws + rload * (T_ * H_) + q * 8;
    half8 a0[4];
#pragma unroll
    for (int kc = 0; kc < 4; ++kc)
      a0[kc] = *(const half8*)(h0p + kc * 32);

#pragma unroll 1
    for (int t = 0; t < T_; ++t) {
      const int tn = (t + 1 < T_) ? (t + 1) : t;
      half8 a0n[4];
#pragma unroll
      for (int kc = 0; kc < 4; ++kc)          // prefetch next h0_t
        a0n[kc] = *(const half8*)(h0p + tn * H_ + kc * 32);

      float4_t acc[4];
#pragma unroll
      for (int j = 0; j < 4; ++j)
        acc[j] = (float4_t){bias[j], bias[j], bias[j], bias[j]};
#pragma unroll
      for (int kc = 0; kc < 4; ++kc)
#pragma unroll
        for (int j = 0; j < 4; ++j)
          acc[j] = __builtin_amdgcn_mfma_f32_16x16x32_f16(a0[kc], bwih[j][kc], acc[j], 0, 0, 0);
#pragma unroll
      for (int kc = 0; kc < 4; ++kc)
#pragma unroll
        for (int j = 0; j < 4; ++j)
          acc[j] = __builtin_amdgcn_mfma_f32_16x16x32_f16(ah[kc], bwhh[j][kc], acc[j], 0, 0, 0);

      _Float16* hb = lds_h[t & 1];
#pragma unroll
      for (int rr = 0; rr < 2; ++rr) {
        const int ri = rsh + rr;
        const float gi = fsig(acc[0][ri]);
        const float gf = fsig(acc[1][ri]);
        const float gg = ftanh_(acc[2][ri]);
        const float go = fsig(acc[3][ri]);
        float& cc = rr ? c1v : c0v;
        cc = gf * cc + gi * gg;
        const float hv = go * ftanh_(cc);
        if (rr) hl1 = hv; else hl0 = hv;
        hb[(rowq + ri) * 136 + w * 16 + n] = (_Float16)hv;
      }
      __syncthreads();
#pragma unroll
      for (int kc = 0; kc < 4; ++kc)
        ah[kc] = *(const half8*)(hb + (n & 7) * 136 + kc * 32 + q * 8);
#pragma unroll
      for (int kc = 0; kc < 4; ++kc) a0[kc] = a0n[kc];
    }

    // FC head: out[row] = sum_c h1_last[row][c] * Wfc[c] + bfc
    float p0 = hl0 * wfc, p1 = hl1 * wfc;
#pragma unroll
    for (int m = 1; m < 16; m <<= 1) {   // reduce across the 16 n-lanes
      p0 += __shfl_xor(p0, m);
      p1 += __shfl_xor(p1, m);
    }
    if (n == 0) {
      lds_fc[w][rowq + rsh + 0] = p0;
      lds_fc[w][rowq + rsh + 1] = p1;
    }
    __syncthreads();
    if (tid < 8) {
      float s = bfc[0];
#pragma unroll
      for (int wv = 0; wv < 8; ++wv) s += lds_fc[wv][tid];
      out[rbase + tid] = s;
    }
  }
}

extern "C" void kernel_launch(void* const* d_in, const int* in_sizes, int n_in,
                              void* d_out, int out_size, void* d_ws, size_t ws_size,
                              hipStream_t stream) {
  const float* x    = (const float*)d_in[0];
  const float* Wih0 = (const float*)d_in[1];
  const float* Whh0 = (const float*)d_in[2];
  const float* b0   = (const float*)d_in[3];
  const float* Wih1 = (const float*)d_in[4];
  const float* Whh1 = (const float*)d_in[5];
  const float* b1   = (const float*)d_in[6];
  const float* Wfc  = (const float*)d_in[7];
  const float* bfc  = (const float*)d_in[8];
  float* outp = (float*)d_out;
  _Float16* h0ws = (_Float16*)d_ws;   // requires ws_size >= 268435456 B

  lstm_fused<<<B_ / 8, 512, 0, stream>>>(x, Wih0, Whh0, b0, Wih1, Whh1, b1,
                                         Wfc, bfc, outp, h0ws);
}

// Round 2
// 1084.234 us; speedup vs baseline: 1.1804x; 1.1804x over previous
//
#include <hip/hip_runtime.h>
#include <stdint.h>

// LSTM: B=2048, T=512, F=32, H=128, G=4H=512. 2 layers + FC(128->1).
// One WG (512 thr, 8 waves) per 8 batch rows; 256 WGs = 1/CU.
// mfma_f32_16x16x32_f16, weights held in VGPR/AGPR as B-fragments.
// Wave w owns gate tiles {w, 8+w, 16+w, 24+w} == i,f,g,o for h-cols [16w,16w+16).
// M=16 tile: 8 real rows duplicated (A row = lane&7); each lane finalizes 2 rows.
// Round 2: 2-deep acc pipeline (ih-MFMA of t+1 overlaps gates of t), bias as
// MFMA C operand, LDS stride 144 (2-way banks only), lgkm-only barrier.
// Layer-0 h sequence staged in d_ws as fp16 (2048*512*128*2 = 256 MiB).

#define B_ 2048
#define T_ 512
#define F_ 32
#define H_ 128
#define LSTR 144   // halves per LDS row: dwords 72 -> bank base (8r+4q)%32, 2-way only

typedef _Float16 half8 __attribute__((ext_vector_type(8)));
typedef float float4_t __attribute__((ext_vector_type(4)));

// lgkm-only barrier: __syncthreads would also drain vmcnt(0), serializing the
// global prefetch. LDS producer->consumer only needs lgkmcnt(0).
#define BARRIER_LGKM() asm volatile("s_waitcnt lgkmcnt(0)\n\ts_barrier" ::: "memory")

__device__ __forceinline__ float fsig(float xv) {
  return __builtin_amdgcn_rcpf(1.0f + __expf(-xv));
}
// overflow-safe tanh: e=inf -> 1, e=0 -> -1 (no NaN)
__device__ __forceinline__ float ftanh_(float xv) {
  float e = __expf(2.0f * xv);
  return 1.0f - 2.0f * __builtin_amdgcn_rcpf(1.0f + e);
}
__device__ __forceinline__ half8 cvt2f4(float4_t a, float4_t b) {
  half8 r;
  r[0] = (_Float16)a[0]; r[1] = (_Float16)a[1]; r[2] = (_Float16)a[2]; r[3] = (_Float16)a[3];
  r[4] = (_Float16)b[0]; r[5] = (_Float16)b[1]; r[6] = (_Float16)b[2]; r[7] = (_Float16)b[3];
  return r;
}
__device__ __forceinline__ half8 load8cvt(const float* p) {
  return cvt2f4(*(const float4_t*)p, *(const float4_t*)(p + 4));
}

__global__ __launch_bounds__(512, 2) void lstm_fused(
    const float* __restrict__ x, const float* __restrict__ Wih0,
    const float* __restrict__ Whh0, const float* __restrict__ b0,
    const float* __restrict__ Wih1, const float* __restrict__ Whh1,
    const float* __restrict__ b1, const float* __restrict__ Wfc,
    const float* __restrict__ bfc, float* __restrict__ out,
    _Float16* __restrict__ h0ws)
{
  __shared__ __attribute__((aligned(16))) _Float16 lds_h[2][8 * LSTR];
  __shared__ float lds_fc[8][8];

  const int tid  = threadIdx.x;
  const int w    = tid >> 6;
  const int lane = tid & 63;
  const int n    = lane & 15;
  const int q    = lane >> 4;
  const int rbase = (int)blockIdx.x * 8;
  const int rload = rbase + (n & 7);
  const int rsh  = (q >> 1) * 2;
  const int rowq = (q & 1) * 4;
  const int colg = w * 16 + n;
  const int aoff = (n & 7) * LSTR + q * 8;   // A-frag read offset (halves)

  // ---------------- Phase 1 : layer 0 (x -> h0 sequence in ws) ----------------
  {
    half8 bwih[4];
    half8 bwhh[4][4];
    float4_t biasC[4];
#pragma unroll
    for (int j = 0; j < 4; ++j) {
      const int g = (j * 8 + w) * 16 + n;
      bwih[j] = load8cvt(Wih0 + g * F_ + q * 8);
      const float bb = b0[g];
      biasC[j] = (float4_t){bb, bb, bb, bb};
#pragma unroll
      for (int kc = 0; kc < 4; ++kc)
        bwhh[j][kc] = load8cvt(Whh0 + g * H_ + kc * 32 + q * 8);
    }
    for (int i = tid; i < 8 * LSTR; i += 512) lds_h[1][i] = (_Float16)0.0f;

    float c0v = 0.f, c1v = 0.f;
    const float* xptr = x + rload * (T_ * F_) + q * 8;
    _Float16* hw0 = h0ws + (rbase + rowq + rsh)     * (T_ * H_) + colg;
    _Float16* hw1 = h0ws + (rbase + rowq + rsh + 1) * (T_ * H_) + colg;

    float4_t accA[4], accB[4];
    {
      half8 ax0 = load8cvt(xptr);   // x_0
#pragma unroll
      for (int j = 0; j < 4; ++j)
        accA[j] = __builtin_amdgcn_mfma_f32_16x16x32_f16(ax0, bwih[j], biasC[j], 0, 0, 0);
    }
    float4_t xrA = *(const float4_t*)(xptr + F_);
    float4_t xrB = *(const float4_t*)(xptr + F_ + 4);
    BARRIER_LGKM();

#define P1_BODY(T0, RB, WB, ACC_C, ACC_N)                                      \
    {                                                                          \
      half8 ah[4];                                                             \
      _Float16* hbR = lds_h[RB];                                               \
      _Float16* hbW = lds_h[WB];                                               \
      _Pragma("unroll")                                                        \
      for (int kc = 0; kc < 4; ++kc)                                           \
        ah[kc] = *(const half8*)(hbR + aoff + kc * 32);                        \
      _Pragma("unroll")                                                        \
      for (int kc = 0; kc < 4; ++kc)                                           \
        _Pragma("unroll")                                                      \
        for (int j = 0; j < 4; ++j)                                            \
          ACC_C[j] = __builtin_amdgcn_mfma_f32_16x16x32_f16(ah[kc], bwhh[j][kc], ACC_C[j], 0, 0, 0); \
      { half8 axn = cvt2f4(xrA, xrB);                                          \
        _Pragma("unroll")                                                      \
        for (int j = 0; j < 4; ++j)                                            \
          ACC_N[j] = __builtin_amdgcn_mfma_f32_16x16x32_f16(axn, bwih[j], biasC[j], 0, 0, 0); } \
      { const int tf = ((T0) + 2 < T_) ? ((T0) + 2) : (T_ - 1);                \
        xrA = *(const float4_t*)(xptr + tf * F_);                              \
        xrB = *(const float4_t*)(xptr + tf * F_ + 4); }                        \
      _Pragma("unroll")                                                        \
      for (int rr = 0; rr < 2; ++rr) {                                         \
        const int ri = rsh + rr;                                               \
        const float gi = fsig(ACC_C[0][ri]);                                   \
        const float gf = fsig(ACC_C[1][ri]);                                   \
        const float gg = ftanh_(ACC_C[2][ri]);                                 \
        const float go = fsig(ACC_C[3][ri]);                                   \
        float& cc = rr ? c1v : c0v;                                            \
        cc = gf * cc + gi * gg;                                                \
        const float hv = go * ftanh_(cc);                                      \
        const _Float16 h16 = (_Float16)hv;                                     \
        hbW[(rowq + ri) * LSTR + colg] = h16;                                  \
        *(rr ? hw1 : hw0) = h16;                                               \
      }                                                                        \
      hw0 += H_; hw1 += H_;                                                    \
      BARRIER_LGKM();                                                          \
    }

#pragma unroll 1
    for (int t = 0; t < T_; t += 2) {
      P1_BODY(t, 1, 0, accA, accB)
      P1_BODY(t + 1, 0, 1, accB, accA)
    }
#undef P1_BODY
  }

  __syncthreads();   // full drain: phase-1 global stores must be visible below

  // ---------------- Phase 2 : layer 1 + FC ----------------
  {
    half8 bwih[4][4], bwhh[4][4];
    float4_t biasC[4];
#pragma unroll
    for (int j = 0; j < 4; ++j) {
      const int g = (j * 8 + w) * 16 + n;
      const float bb = b1[g];
      biasC[j] = (float4_t){bb, bb, bb, bb};
#pragma unroll
      for (int kc = 0; kc < 4; ++kc) {
        bwih[j][kc] = load8cvt(Wih1 + g * H_ + kc * 32 + q * 8);
        bwhh[j][kc] = load8cvt(Whh1 + g * H_ + kc * 32 + q * 8);
      }
    }
    for (int i = tid; i < 8 * LSTR; i += 512) lds_h[1][i] = (_Float16)0.0f;

    const float wfc = Wfc[colg];
    float c0v = 0.f, c1v = 0.f, hl0 = 0.f, hl1 = 0.f;
    const _Float16* h0p = h0ws + rload * (T_ * H_) + q * 8;

    half8 a0A[4], a0B[4];
#pragma unroll
    for (int kc = 0; kc < 4; ++kc) a0A[kc] = *(const half8*)(h0p + kc * 32);
    float4_t accA[4], accB[4];
#pragma unroll
    for (int kc = 0; kc < 4; ++kc)
#pragma unroll
      for (int j = 0; j < 4; ++j)
        accA[j] = __builtin_amdgcn_mfma_f32_16x16x32_f16(
            a0A[kc], bwih[j][kc], kc == 0 ? biasC[j] : accA[j], 0, 0, 0);
#pragma unroll
    for (int kc = 0; kc < 4; ++kc) a0B[kc] = *(const half8*)(h0p + H_ + kc * 32);
    BARRIER_LGKM();

#define P2_BODY(T0, RB, WB, ACC_C, ACC_N, A0N, A0F)                            \
    {                                                                          \
      half8 ah[4];                                                             \
      _Float16* hbR = lds_h[RB];                                               \
      _Float16* hbW = lds_h[WB];                                               \
      _Pragma("unroll")                                                        \
      for (int kc = 0; kc < 4; ++kc)                                           \
        ah[kc] = *(const half8*)(hbR + aoff + kc * 32);                        \
      _Pragma("unroll")                                                        \
      for (int kc = 0; kc < 4; ++kc)                                           \
        _Pragma("unroll")                                                      \
        for (int j = 0; j < 4; ++j)                                            \
          ACC_C[j] = __builtin_amdgcn_mfma_f32_16x16x32_f16(ah[kc], bwhh[j][kc], ACC_C[j], 0, 0, 0); \
      _Pragma("unroll")                                                        \
      for (int kc = 0; kc < 4; ++kc)                                           \
        _Pragma("unroll")                                                      \
        for (int j = 0; j < 4; ++j)                                            \
          ACC_N[j] = __builtin_amdgcn_mfma_f32_16x16x32_f16(                   \
              A0N[kc], bwih[j][kc], kc == 0 ? biasC[j] : ACC_N[j], 0, 0, 0);   \
      { const int tf = ((T0) + 2 < T_) ? ((T0) + 2) : (T_ - 1);                \
        _Pragma("unroll")                                                      \
        for (int kc = 0; kc < 4; ++kc)                                         \
          A0F[kc] = *(const half8*)(h0p + tf * H_ + kc * 32); }                \
      _Pragma("unroll")                                                        \
      for (int rr = 0; rr < 2; ++rr) {                                         \
        const int ri = rsh + rr;                                               \
        const float gi = fsig(ACC_C[0][ri]);                                   \
        const float gf = fsig(ACC_C[1][ri]);                                   \
        const float gg = ftanh_(ACC_C[2][ri]);                                 \
        const float go = fsig(ACC_C[3][ri]);                                   \
        float& cc = rr ? c1v : c0v;                                            \
        cc = gf * cc + gi * gg;                                                \
        const float hv = go * ftanh_(cc);                                      \
        if (rr) hl1 = hv; else hl0 = hv;                                       \
        hbW[(rowq + ri) * LSTR + colg] = (_Float16)hv;                         \
      }                                                                        \
      BARRIER_LGKM();                                                          \
    }

#pragma unroll 1
    for (int t = 0; t < T_; t += 2) {
      P2_BODY(t, 1, 0, accA, accB, a0B, a0A)
      P2_BODY(t + 1, 0, 1, accB, accA, a0A, a0B)
    }
#undef P2_BODY

    // FC head: out[row] = sum_c h1_last[row][c] * Wfc[c] + bfc
    float p0 = hl0 * wfc, p1 = hl1 * wfc;
#pragma unroll
    for (int m = 1; m < 16; m <<= 1) {
      p0 += __shfl_xor(p0, m);
      p1 += __shfl_xor(p1, m);
    }
    if (n == 0) {
      lds_fc[w][rowq + rsh + 0] = p0;
      lds_fc[w][rowq + rsh + 1] = p1;
    }
    __syncthreads();
    if (tid < 8) {
      float s = bfc[0];
#pragma unroll
      for (int wv = 0; wv < 8; ++wv) s += lds_fc[wv][tid];
      out[rbase + tid] = s;
    }
  }
}

extern "C" void kernel_launch(void* const* d_in, const int* in_sizes, int n_in,
                              void* d_out, int out_size, void* d_ws, size_t ws_size,
                              hipStream_t stream) {
  const float* x    = (const float*)d_in[0];
  const float* Wih0 = (const float*)d_in[1];
  const float* Whh0 = (const float*)d_in[2];
  const float* b0   = (const float*)d_in[3];
  const float* Wih1 = (const float*)d_in[4];
  const float* Whh1 = (const float*)d_in[5];
  const float* b1   = (const float*)d_in[6];
  const float* Wfc  = (const float*)d_in[7];
  const float* bfc  = (const float*)d_in[8];
  float* outp = (float*)d_out;
  _Float16* h0ws = (_Float16*)d_ws;   // requires ws_size >= 268435456 B

  lstm_fused<<<B_ / 8, 512, 0, stream>>>(x, Wih0, Whh0, b0, Wih1, Whh1, b1,
                                         Wfc, bfc, outp, h0ws);
}

// Round 3
// 1050.791 us; speedup vs baseline: 1.2179x; 1.0318x over previous
//
#include <hip/hip_runtime.h>
#include <stdint.h>

// Fused 2-layer LSTM: B=2048, T=512, F=32, H=128, G=512. One WG (512 thr,
// 8 waves) per 8 batch rows; 256 WGs = 1/CU. Single 513-iteration loop:
// iteration tau runs layer-0 step tau AND layer-1 step tau-1 (skewed), so the
// two layers' MFMA/VALU streams interleave and hide each other's latency.
// h0 passes through LDS only (no HBM staging). L0-hh and L1-ih share the same
// A-fragment (both consume h0(tau-1)). Weights: Wih0/Whh0/Whh1 fragments in
// VGPR/AGPR; Wih1 streamed per-iter from a 133 KB bank-padded LDS image
// (per-lane address loop-invariant, immediate offsets). Bias folded into the
// gate transcendental prologue (log2-domain fma). ws unused.

#define B_ 2048
#define T_ 512
#define F_ 32
#define H_ 128
#define LSTR 144                 // halves per h-buffer row
#define H0SZ (8 * LSTR)          // halves per h buffer
#define WIH1_NSTR 520            // halves: 1040 B n-stride -> 2-way banks only
#define WIH1_WSTR (16 * WIH1_NSTR)

#define LOG2E 1.4426950408889634f

typedef _Float16 half8 __attribute__((ext_vector_type(8)));
typedef float float4_t __attribute__((ext_vector_type(4)));

// lgkm-only barrier: don't drain vmcnt (global x prefetch stays in flight)
#define BARRIER_LGKM() asm volatile("s_waitcnt lgkmcnt(0)\n\ts_barrier" ::: "memory")

__device__ __forceinline__ float fexp2(float x) {
  float r; asm("v_exp_f32 %0, %1" : "=v"(r) : "v"(x)); return r;
}
__device__ __forceinline__ float frcp(float x) { return __builtin_amdgcn_rcpf(x); }

__device__ __forceinline__ half8 cvt2f4(float4_t a, float4_t b) {
  half8 r;
  r[0] = (_Float16)a[0]; r[1] = (_Float16)a[1]; r[2] = (_Float16)a[2]; r[3] = (_Float16)a[3];
  r[4] = (_Float16)b[0]; r[5] = (_Float16)b[1]; r[6] = (_Float16)b[2]; r[7] = (_Float16)b[3];
  return r;
}
__device__ __forceinline__ half8 load8cvt(const float* p) {
  return cvt2f4(*(const float4_t*)p, *(const float4_t*)(p + 4));
}

__global__ __launch_bounds__(512, 2) void lstm_fused(
    const float* __restrict__ x, const float* __restrict__ Wih0,
    const float* __restrict__ Whh0, const float* __restrict__ b0,
    const float* __restrict__ Wih1, const float* __restrict__ Whh1,
    const float* __restrict__ b1, const float* __restrict__ Wfc,
    const float* __restrict__ bfc, float* __restrict__ out)
{
  __shared__ __attribute__((aligned(16))) _Float16 lds_wih1[8 * WIH1_WSTR]; // 133120 B
  __shared__ __attribute__((aligned(16))) _Float16 lds_h0[2 * H0SZ];        // 4608 B
  __shared__ __attribute__((aligned(16))) _Float16 lds_h1[2 * H0SZ];        // 4608 B
  __shared__ float lds_fc[8][8];

  const int tid  = threadIdx.x;
  const int w    = tid >> 6;
  const int lane = tid & 63;
  const int n    = lane & 15;
  const int q    = lane >> 4;
  const int rbase = (int)blockIdx.x * 8;
  const int rload = rbase + (n & 7);
  const int rsh  = (q >> 1) * 2;            // acc regs this lane finalizes
  const int rowq = (q & 1) * 4;             // base output row
  const int colg = w * 16 + n;              // this lane's h-column
  const int aoff = (n & 7) * LSTR + q * 8;  // A-frag read offset (halves)

  // ---- setup: weights -> regs, Wih1 -> LDS (swizzled), folded biases ----
  half8 bwih0[4], bwhh0[4][4], bwhh1[4][4];
  _Float16* wslot = lds_wih1 + w * WIH1_WSTR + n * WIH1_NSTR + q * 8;
#pragma unroll
  for (int j = 0; j < 4; ++j) {
    const int g = j * H_ + colg;            // == (j*8+w)*16+n
    bwih0[j] = load8cvt(Wih0 + g * F_ + q * 8);
#pragma unroll
    for (int kc = 0; kc < 4; ++kc) {
      bwhh0[j][kc] = load8cvt(Whh0 + g * H_ + kc * 32 + q * 8);
      bwhh1[j][kc] = load8cvt(Whh1 + g * H_ + kc * 32 + q * 8);
      *(half8*)(wslot + (j * 4 + kc) * 32) = load8cvt(Wih1 + g * H_ + kc * 32 + q * 8);
    }
  }
  // folded gate biases (log2 domain): sig(z+b)=rcp(1+2^(-z*log2e - b*log2e)),
  // tanh(z+b)=1-2*rcp(1+2^(2z*log2e + 2b*log2e))
  const float cI0 = -b0[0 * H_ + colg] * LOG2E;
  const float cF0 = -b0[1 * H_ + colg] * LOG2E;
  const float cG0 =  b0[2 * H_ + colg] * (2.0f * LOG2E);
  const float cO0 = -b0[3 * H_ + colg] * LOG2E;
  const float cI1 = -b1[0 * H_ + colg] * LOG2E;
  const float cF1 = -b1[1 * H_ + colg] * LOG2E;
  const float cG1 =  b1[2 * H_ + colg] * (2.0f * LOG2E);
  const float cO1 = -b1[3 * H_ + colg] * LOG2E;
  const float wfc = Wfc[colg];

  for (int i = tid; i < 2 * H0SZ; i += 512) { lds_h0[i] = (_Float16)0.0f; lds_h1[i] = (_Float16)0.0f; }
  __syncthreads();

  const float4_t zC = {0.f, 0.f, 0.f, 0.f};
  float c00 = 0.f, c01 = 0.f;      // layer-0 cell state (2 rows)
  float c10 = 0.f, c11 = 0.f;      // layer-1 cell state
  float hl0 = 0.f, hl1 = 0.f;      // last layer-1 h

  const float* xptr = x + rload * (T_ * F_) + q * 8;
  float4_t xrA = *(const float4_t*)(xptr);
  float4_t xrB = *(const float4_t*)(xptr + 4);

#pragma unroll 1
  for (int tau = 0; tau <= T_; ++tau) {
    const int pw = tau & 1;
    _Float16* h0rd = lds_h0 + (pw ^ 1) * H0SZ;   // h0(tau-1)
    _Float16* h0wr = lds_h0 + pw * H0SZ;         // h0(tau)
    _Float16* h1rd = lds_h1 + pw * H0SZ;         // h1(tau-2)
    _Float16* h1wr = lds_h1 + (pw ^ 1) * H0SZ;   // h1(tau-1)
    const bool do0 = (tau < T_), do1 = (tau >= 1);

    half8 ah[4];                                  // h0(tau-1): shared A-frag
#pragma unroll
    for (int kc = 0; kc < 4; ++kc)
      ah[kc] = *(const half8*)(h0rd + aoff + kc * 32);

    float4_t acc0[4], acc1[4];
    if (do0) {                                    // layer 0, step tau
      half8 ax = cvt2f4(xrA, xrB);
#pragma unroll
      for (int j = 0; j < 4; ++j)
        acc0[j] = __builtin_amdgcn_mfma_f32_16x16x32_f16(ax, bwih0[j], zC, 0, 0, 0);
#pragma unroll
      for (int kc = 0; kc < 4; ++kc)
#pragma unroll
        for (int j = 0; j < 4; ++j)
          acc0[j] = __builtin_amdgcn_mfma_f32_16x16x32_f16(ah[kc], bwhh0[j][kc], acc0[j], 0, 0, 0);
      const int tn = (tau + 1 < T_) ? tau + 1 : T_ - 1;   // x prefetch
      xrA = *(const float4_t*)(xptr + tn * F_);
      xrB = *(const float4_t*)(xptr + tn * F_ + 4);
    }
    if (do1) {                                    // layer 1, step tau-1
      half8 a1h[4];
#pragma unroll
      for (int kc = 0; kc < 4; ++kc)
        a1h[kc] = *(const half8*)(h1rd + aoff + kc * 32);
#pragma unroll
      for (int kc = 0; kc < 4; ++kc) {            // ih: Wih1 frags from LDS
        half8 f0 = *(const half8*)(wslot + (0 * 4 + kc) * 32);
        half8 f1 = *(const half8*)(wslot + (1 * 4 + kc) * 32);
        half8 f2 = *(const half8*)(wslot + (2 * 4 + kc) * 32);
        half8 f3 = *(const half8*)(wslot + (3 * 4 + kc) * 32);
        acc1[0] = __builtin_amdgcn_mfma_f32_16x16x32_f16(ah[kc], f0, kc == 0 ? zC : acc1[0], 0, 0, 0);
        acc1[1] = __builtin_amdgcn_mfma_f32_16x16x32_f16(ah[kc], f1, kc == 0 ? zC : acc1[1], 0, 0, 0);
        acc1[2] = __builtin_amdgcn_mfma_f32_16x16x32_f16(ah[kc], f2, kc == 0 ? zC : acc1[2], 0, 0, 0);
        acc1[3] = __builtin_amdgcn_mfma_f32_16x16x32_f16(ah[kc], f3, kc == 0 ? zC : acc1[3], 0, 0, 0);
      }
#pragma unroll
      for (int kc = 0; kc < 4; ++kc)
#pragma unroll
        for (int j = 0; j < 4; ++j)
          acc1[j] = __builtin_amdgcn_mfma_f32_16x16x32_f16(a1h[kc], bwhh1[j][kc], acc1[j], 0, 0, 0);
    }

    if (do0) {                                    // layer-0 gates
#pragma unroll
      for (int rr = 0; rr < 2; ++rr) {
        const int ri = rsh + rr;
        const float gi = frcp(1.0f + fexp2(__builtin_fmaf(acc0[0][ri], -LOG2E, cI0)));
        const float gf = frcp(1.0f + fexp2(__builtin_fmaf(acc0[1][ri], -LOG2E, cF0)));
        const float gg = 1.0f - 2.0f * frcp(1.0f + fexp2(__builtin_fmaf(acc0[2][ri], 2.0f * LOG2E, cG0)));
        const float go = frcp(1.0f + fexp2(__builtin_fmaf(acc0[3][ri], -LOG2E, cO0)));
        float& cc = rr ? c01 : c00;
        cc = __builtin_fmaf(gf, cc, gi * gg);
        const float th = 1.0f - 2.0f * frcp(1.0f + fexp2(cc * (2.0f * LOG2E)));
        h0wr[(rowq + ri) * LSTR + colg] = (_Float16)(go * th);
      }
    }
    if (do1) {                                    // layer-1 gates
#pragma unroll
      for (int rr = 0; rr < 2; ++rr) {
        const int ri = rsh + rr;
        const float gi = frcp(1.0f + fexp2(__builtin_fmaf(acc1[0][ri], -LOG2E, cI1)));
        const float gf = frcp(1.0f + fexp2(__builtin_fmaf(acc1[1][ri], -LOG2E, cF1)));
        const float gg = 1.0f - 2.0f * frcp(1.0f + fexp2(__builtin_fmaf(acc1[2][ri], 2.0f * LOG2E, cG1)));
        const float go = frcp(1.0f + fexp2(__builtin_fmaf(acc1[3][ri], -LOG2E, cO1)));
        float& cc = rr ? c11 : c10;
        cc = __builtin_fmaf(gf, cc, gi * gg);
        const float th = 1.0f - 2.0f * frcp(1.0f + fexp2(cc * (2.0f * LOG2E)));
        const float hv = go * th;
        h1wr[(rowq + ri) * LSTR + colg] = (_Float16)hv;
        if (rr) hl1 = hv; else hl0 = hv;          // last write wins = h1(T-1)
      }
    }
    BARRIER_LGKM();
  }

  // ---- FC head: out[row] = sum_c h1_last[row][c]*Wfc[c] + bfc ----
  float p0 = hl0 * wfc, p1 = hl1 * wfc;
#pragma unroll
  for (int m = 1; m < 16; m <<= 1) {
    p0 += __shfl_xor(p0, m);
    p1 += __shfl_xor(p1, m);
  }
  if (n == 0) {
    lds_fc[w][rowq + rsh + 0] = p0;
    lds_fc[w][rowq + rsh + 1] = p1;
  }
  __syncthreads();
  if (tid < 8) {
    float s = bfc[0];
#pragma unroll
    for (int wv = 0; wv < 8; ++wv) s += lds_fc[wv][tid];
    out[rbase + tid] = s;
  }
}

extern "C" void kernel_launch(void* const* d_in, const int* in_sizes, int n_in,
                              void* d_out, int out_size, void* d_ws, size_t ws_size,
                              hipStream_t stream) {
  const float* x    = (const float*)d_in[0];
  const float* Wih0 = (const float*)d_in[1];
  const float* Whh0 = (const float*)d_in[2];
  const float* b0   = (const float*)d_in[3];
  const float* Wih1 = (const float*)d_in[4];
  const float* Whh1 = (const float*)d_in[5];
  const float* b1   = (const float*)d_in[6];
  const float* Wfc  = (const float*)d_in[7];
  const float* bfc  = (const float*)d_in[8];
  float* outp = (float*)d_out;
  (void)d_ws; (void)ws_size;

  lstm_fused<<<B_ / 8, 512, 0, stream>>>(x, Wih0, Whh0, b0, Wih1, Whh1, b1,
                                         Wfc, bfc, outp);
}